// Round 6
// baseline (274.917 us; speedup 1.0000x reference)
//
#include <hip/hip_runtime.h>

typedef _Float16 f16;
typedef __attribute__((ext_vector_type(8))) _Float16 half8;
typedef __attribute__((ext_vector_type(4))) _Float16 half4;
typedef __attribute__((ext_vector_type(4))) float floatx4;
typedef unsigned int uint32;
typedef __attribute__((ext_vector_type(4))) uint32 uint4v;

#define MFMA16(a, b, c) __builtin_amdgcn_mfma_f32_16x16x32_f16((a), (b), (c), 0, 0, 0)

constexpr int B_ = 4, M_ = 1024, N_ = 4096, DQ_ = 512, DC_ = 512, H_ = 8, DH_ = 64, D_ = 512;
constexpr int KP_ = 576;       // K row stride (halves)
constexpr int VP_ = 4224;      // Vt row stride (halves)
constexpr int NSPLIT = 4;      // proven L2-coherent split
constexpr float QSC_ = 0.18033688011112042f;  // 0.125 * log2(e)

typedef __attribute__((address_space(1))) const void glds_g;
typedef __attribute__((address_space(3))) void glds_l;
__device__ __forceinline__ void g2lds16(const void* g, void* l) {
    __builtin_amdgcn_global_load_lds((glds_g*)g, (glds_l*)l, 16, 0, 0);
}

// ---- 64x64 f32->f16 transpose tile through LDS (device helper) ----
__device__ __forceinline__ void wtr_tile(const float* __restrict__ src, f16* __restrict__ dst,
                                         int Nout, int bx, int by, int tid) {
    __shared__ __align__(16) f16 Ts[64][72];
    const int n0 = bx * 64, k0 = by * 64;
    {
        int kr = tid >> 2, q4 = tid & 3;
        const float* sp = src + (size_t)(k0 + kr) * Nout + n0 + q4 * 16;
        float4 x0 = *(const float4*)(sp + 0), x1 = *(const float4*)(sp + 4);
        float4 x2 = *(const float4*)(sp + 8), x3 = *(const float4*)(sp + 12);
        half8 h0, h1;
        h0[0]=(f16)x0.x; h0[1]=(f16)x0.y; h0[2]=(f16)x0.z; h0[3]=(f16)x0.w;
        h0[4]=(f16)x1.x; h0[5]=(f16)x1.y; h0[6]=(f16)x1.z; h0[7]=(f16)x1.w;
        h1[0]=(f16)x2.x; h1[1]=(f16)x2.y; h1[2]=(f16)x2.z; h1[3]=(f16)x2.w;
        h1[4]=(f16)x3.x; h1[5]=(f16)x3.y; h1[6]=(f16)x3.z; h1[7]=(f16)x3.w;
        *(half8*)&Ts[kr][q4 * 16] = h0;
        *(half8*)&Ts[kr][q4 * 16 + 8] = h1;
    }
    __syncthreads();
    {
        int nr = tid >> 2, q = tid & 3;
        half8 h0, h1;
#pragma unroll
        for (int j = 0; j < 8; j++) { h0[j] = Ts[q * 16 + j][nr]; h1[j] = Ts[q * 16 + 8 + j][nr]; }
        f16* dp = dst + (size_t)(n0 + nr) * 512 + k0 + q * 16;
        *(half8*)(dp + 0) = h0;
        *(half8*)(dp + 8) = h1;
    }
}

// ---------------- prep mega-kernel ----------------
// mask region rewritten: single-round 16-elem/thread pack (uint4 loads + shfl merge)
// instead of 16 rounds of {scalar load + ballot + masked store}.
__global__ __launch_bounds__(256)
void prep_k(const void* __restrict__ mask, uint32* __restrict__ bits,
            const float* __restrict__ left, f16* __restrict__ leftb,
            const float* __restrict__ right, f16* __restrict__ rightb,
            const float* __restrict__ Wq, f16* __restrict__ wqt,
            const float* __restrict__ Wkv, f16* __restrict__ wkvt,
            const float* __restrict__ Wout, f16* __restrict__ woutt) {
    const int blk = blockIdx.x, tid = threadIdx.x;
    if (blk < 4096) {
        // dtype detect on the block's OWN 4KB word-window (in-bounds both layouts)
        __shared__ int s_bad;
        if (tid == 0) s_bad = 0;
        __syncthreads();
        const uint32* w = (const uint32*)mask + (size_t)blk * 1024;
        int bad = 0;
#pragma unroll
        for (int j = 0; j < 4; j++) bad |= (w[tid * 4 + j] & 0xFFFFFFFEu) != 0u;
        if (bad) s_bad = 1;  // benign race: all writers store 1
        __syncthreads();
        const bool bytes_mode = s_bad != 0;
        // thread owns elems [blk*4096 + tid*16, +16)
        uint32 v = 0;
        if (bytes_mode) {
            uint4 x = *(const uint4*)((const unsigned char*)mask + (size_t)blk * 4096 + tid * 16);
            uint32 ws_[4] = {x.x, x.y, x.z, x.w};
#pragma unroll
            for (int k = 0; k < 4; k++)
#pragma unroll
                for (int bb = 0; bb < 4; bb++)
                    v |= (((ws_[k] >> (8 * bb)) & 0xFFu) != 0u ? 1u : 0u) << (k * 4 + bb);
        } else {
            const uint4* p = (const uint4*)((const uint32*)mask + (size_t)blk * 4096 + tid * 16);
            uint4 x0 = p[0], x1 = p[1], x2 = p[2], x3 = p[3];
            uint32 ws_[16] = {x0.x, x0.y, x0.z, x0.w, x1.x, x1.y, x1.z, x1.w,
                              x2.x, x2.y, x2.z, x2.w, x3.x, x3.y, x3.z, x3.w};
#pragma unroll
            for (int k = 0; k < 16; k++) v |= (ws_[k] != 0u ? 1u : 0u) << k;
        }
        uint32 other = (uint32)__shfl_xor((int)v, 1);
        if ((tid & 1) == 0)
            bits[(size_t)blk * 128 + (tid >> 1)] = v | (other << 16);
    } else if (blk < 6144) {
        int i = ((blk - 4096) * 256 + tid) * 4;
        float4 x = *(const float4*)(left + i);
        half4 h; h[0] = (f16)x.x; h[1] = (f16)x.y; h[2] = (f16)x.z; h[3] = (f16)x.w;
        *(half4*)(leftb + i) = h;
    } else if (blk < 14336) {
        int i = ((blk - 6144) * 256 + tid) * 4;
        float4 x = *(const float4*)(right + i);
        half4 h; h[0] = (f16)x.x; h[1] = (f16)x.y; h[2] = (f16)x.z; h[3] = (f16)x.w;
        *(half4*)(rightb + i) = h;
    } else if (blk < 14400) {
        int r = blk - 14336;
        wtr_tile(Wq, wqt, 512, r & 7, r >> 3, tid);
    } else if (blk < 14528) {
        int r = blk - 14400;
        wtr_tile(Wkv, wkvt, 1024, r & 15, r >> 4, tid);
    } else {
        int r = blk - 14528;
        wtr_tile(Wout, woutt, 512, r & 7, r >> 3, tid);
    }
}

// ---------------- fused q-proj + kv-proj GEMM (128x128, BK=64, xor-swizzled LDS) ------------
// XCD-chunked bijective remap (assume xcd = blk % 8): XCD x owns m-rows [16x,16x+16) x ALL n.
// Per-XCD L2 working set: A 16x128KB = 2MB + B 1MB < 4MB -> each A-panel fetched once per XCD
// (before: same-A blocks were 128 apart -> panels refetched; up to ~134MB HBM).
__global__ __launch_bounds__(256)
void gemmqkv_k(const f16* __restrict__ leftb, const f16* __restrict__ wqt,
               const f16* __restrict__ rightb, const f16* __restrict__ wkvt,
               f16* __restrict__ qb, f16* __restrict__ kb, f16* __restrict__ vt) {
    __shared__ __align__(16) f16 As[128 * 64];
    __shared__ __align__(16) f16 Bs[128 * 64];
    const int hw = blockIdx.x, tid = threadIdx.x;
    const int lane = tid & 63, wave = tid >> 6;
    const int qd = lane >> 4, l16 = lane & 15;
    const int wm = wave >> 1, wn = wave & 1;

    // mode: 0 = K-half kv, 1 = V-half kv (swapped), 2 = q
    int mode;
    const f16* A; const f16* Bt; size_t m0, n0;
    if (hw < 1024) {
        const int xcd = hw & 7, slot = hw >> 3;         // slot 0..127
        const int mi_ = xcd * 16 + (slot & 15);         // 0..127: 16 m-rows per XCD
        const int ni_ = slot >> 4;                      // 0..7: all n on each XCD
        size_t rows = (size_t)mi_ * 128, cols = (size_t)ni_ * 128;
        if (cols < 512) { mode = 0; A = rightb; m0 = rows; Bt = wkvt;   n0 = cols; }
        else            { mode = 1; A = wkvt;   m0 = cols; Bt = rightb; n0 = rows; }
    } else {
        const int r = hw - 1024;
        const int xcd = r & 7, slot = r >> 3;           // slot 0..15
        const int mi_ = xcd * 4 + (slot & 3);           // 0..31
        const int ni_ = slot >> 2;                      // 0..3
        mode = 2; A = leftb; Bt = wqt;
        m0 = (size_t)mi_ * 128; n0 = (size_t)ni_ * 128;
    }

    size_t goff[4];
    f16 *la[4], *lb[4];
#pragma unroll
    for (int i = 0; i < 4; i++) {
        int c = i * 256 + wave * 64 + lane;
        int row = c >> 3, col8 = (c & 7) ^ (row & 7);
        goff[i] = (size_t)row * 512 + col8 * 8;
        la[i] = As + (size_t)(i * 256 + wave * 64) * 8;
        lb[i] = Bs + (size_t)(i * 256 + wave * 64) * 8;
    }
    const f16* Ab = A + m0 * 512;
    const f16* Bb = Bt + n0 * 512;

    floatx4 acc[4][4] = {};

    for (int k0 = 0; k0 < 512; k0 += 64) {
        __syncthreads();
#pragma unroll
        for (int i = 0; i < 4; i++) g2lds16(Ab + goff[i] + k0, la[i]);
#pragma unroll
        for (int i = 0; i < 4; i++) g2lds16(Bb + goff[i] + k0, lb[i]);
        __syncthreads();
#pragma unroll
        for (int kk = 0; kk < 2; kk++) {
            half8 a[4], b[4];
#pragma unroll
            for (int t = 0; t < 4; t++) {
                int rowa = wm * 64 + t * 16 + l16;
                int rowb = wn * 64 + t * 16 + l16;
                int pa8 = ((kk * 4 + qd) ^ (rowa & 7)) * 8;
                int pb8 = ((kk * 4 + qd) ^ (rowb & 7)) * 8;
                a[t] = *(const half8*)&As[rowa * 64 + pa8];
                b[t] = *(const half8*)&Bs[rowb * 64 + pb8];
            }
#pragma unroll
            for (int mt = 0; mt < 4; mt++)
#pragma unroll
                for (int nt = 0; nt < 4; nt++)
                    acc[mt][nt] = MFMA16(a[mt], b[nt], acc[mt][nt]);
        }
    }

#pragma unroll
    for (int mt = 0; mt < 4; mt++)
#pragma unroll
        for (int nt = 0; nt < 4; nt++)
#pragma unroll
            for (int r = 0; r < 4; r++) {
                size_t mi = m0 + wm * 64 + mt * 16 + qd * 4 + r;  // C/D row index
                size_t ni = n0 + wn * 64 + nt * 16 + l16;         // C/D col index
                float v = acc[mt][nt][r];
                if (mode == 2) {
                    qb[mi * 512 + ni] = (f16)v;
                } else if (mode == 0) {
                    kb[mi * KP_ + ni] = (f16)v;
                } else {
                    int dcol = (int)mi - 512;
                    int hh = dcol >> 6, dh = dcol & 63;
                    size_t bb = ni >> 12, nn = ni & 4095;
                    vt[((bb * H_ + hh) * (size_t)DH_ + dh) * VP_ + nn] = (f16)v;
                }
            }
}

// ---------------- flash attention v6: v4 + in-budget K/V fragment prefetch ----------------
// v5 lesson: schedules needing >64 VGPR under (512,8) spill to scratch (FETCH 293MB).
// v6 adds only next-subtile K-frag prefetch (during exp/pack) and next-sd V-frag prefetch
// (between PV MFMAs): ~+16 regs -> ~48, under the cap. Everything else identical to v4.
__global__ __launch_bounds__(512, 8)
void attn_k(const f16* __restrict__ Qb, const f16* __restrict__ Kb,
            const f16* __restrict__ Vt, const uint32* __restrict__ mb,
            float* __restrict__ Op, float* __restrict__ Lp) {
    const int tid = threadIdx.x;
    const int lane = tid & 63, wave = tid >> 6;     // wave 0..7
    const int qd = lane >> 4, l16 = lane & 15;
    const int bh = blockIdx.x, b = bh >> 3, h = bh & 7;
    const int z = blockIdx.z;
    constexpr int iters = N_ / (64 * NSPLIT);   // 16
    const int n_base = z * iters * 64;
    const int m_base = blockIdx.y * 128 + wave * 16;

    __shared__ __align__(16) f16 Ks[2][64 * 64];   // [n][d] chunks, xor-swizzled
    __shared__ __align__(16) f16 Vs[2][64 * 64];   // [dh][n] chunks, xor-swizzled

    // Q B-operand fragments, pre-scaled by 0.125*log2(e)
    half8 q0, q1;
    {
        const f16* qrow = Qb + ((size_t)(b * M_ + m_base + l16)) * D_ + h * DH_;
        half8 r0 = *(const half8*)(qrow + qd * 8);
        half8 r1 = *(const half8*)(qrow + 32 + qd * 8);
#pragma unroll
        for (int j = 0; j < 8; j++) {
            q0[j] = (f16)((float)r0[j] * QSC_);
            q1[j] = (f16)((float)r1[j] * QSC_);
        }
    }

    floatx4 ot[4] = {};   // O^T: ot[sd][r] = O[m=l16][d = sd*16+qd*4+r]
    float l_acc = 0.0f;

    const uint32* mrow = mb + ((size_t)(b * M_ + m_base + l16)) * (N_ / 32);

    const int srow = wave * 8;
    const int r8 = lane >> 3, p8 = lane & 7;
    const int gc8 = p8 ^ r8;
    const f16* kg = Kb + ((size_t)(b * N_) + srow + r8) * KP_ + h * DH_ + gc8 * 8;
    const f16* vg = Vt + ((size_t)(bh * DH_) + srow + r8) * VP_ + gc8 * 8;

    auto stage = [&](int buf, int n0) {
        g2lds16(kg + (size_t)n0 * KP_, &Ks[buf][srow * 64]);
        g2lds16(vg + n0, &Vs[buf][srow * 64]);
    };

    stage(0, n_base);
    uint2 mmc = *(const uint2*)(mrow + (n_base >> 5));
    int cur = 0;

    const int swz = (l16 & 7);
    const int c0 = (qd ^ swz) * 8;
    const int c1 = ((4 + qd) ^ swz) * 8;

    for (int it = 0; it < iters; it++) {
        const int n0 = n_base + it * 64;
        __syncthreads();
        uint2 mmn;
        if (it + 1 < iters) {
            stage(cur ^ 1, n0 + 64);
            mmn = *(const uint2*)(mrow + ((n0 + 64) >> 5));
        }
        const f16* Kc = &Ks[cur][0];
        const f16* Vc = &Vs[cur][0];

        const uint32 u0 = mmc.x >> (qd * 4);
        const uint32 u1 = mmc.y >> (qd * 4);

        // S^T = K·Q^T per 16-n subtile; K-frags for s+1 prefetched during exp/pack of s
        uint32 pk[4][2];
        half8 kc0 = *(const half8*)&Kc[(l16) * 64 + c0];
        half8 kc1 = *(const half8*)&Kc[(l16) * 64 + c1];
#pragma unroll
        for (int s = 0; s < 4; s++) {
            floatx4 t = {};
            t = MFMA16(kc0, q0, t);
            t = MFMA16(kc1, q1, t);
            if (s < 3) {
                const int ro = ((s + 1) * 16 + l16) * 64;
                kc0 = *(const half8*)&Kc[ro + c0];
                kc1 = *(const half8*)&Kc[ro + c1];
            }
            uint32 us = (s & 2 ? u1 : u0) >> ((s & 1) * 16);
            float e0 = __builtin_amdgcn_exp2f(t[0]);
            float e1 = __builtin_amdgcn_exp2f(t[1]);
            float e2 = __builtin_amdgcn_exp2f(t[2]);
            float e3 = __builtin_amdgcn_exp2f(t[3]);
            e0 = (us & 1u) ? e0 : 0.0f;
            e1 = (us & 2u) ? e1 : 0.0f;
            e2 = (us & 4u) ? e2 : 0.0f;
            e3 = (us & 8u) ? e3 : 0.0f;
            l_acc += (e0 + e1) + (e2 + e3);
            pk[s][0] = __builtin_bit_cast(uint32, __builtin_amdgcn_cvt_pkrtz(e0, e1));
            pk[s][1] = __builtin_bit_cast(uint32, __builtin_amdgcn_cvt_pkrtz(e2, e3));
        }

        // In-register routing: pa[hh] lane(qd,l16) elem j = P[m=l16][n=32hh+8qd+j]
        half8 pa[2];
#pragma unroll
        for (int hh = 0; hh < 2; hh++) {
            uint32 w0, w1, w2, w3;
            {
                auto a = __builtin_amdgcn_permlane32_swap(pk[2 * hh][0], pk[2 * hh + 1][0], false, false);
                auto c = __builtin_amdgcn_permlane16_swap(a[0], a[1], false, false);
                w0 = c[0]; w2 = c[1];
            }
            {
                auto a = __builtin_amdgcn_permlane32_swap(pk[2 * hh][1], pk[2 * hh + 1][1], false, false);
                auto c = __builtin_amdgcn_permlane16_swap(a[0], a[1], false, false);
                w1 = c[0]; w3 = c[1];
            }
            uint4v wv = {w0, w1, w2, w3};
            pa[hh] = __builtin_bit_cast(half8, wv);
        }

        // O^T += V^T @ P^T; V-frags for sd+1 prefetched between the two MFMAs of sd
        half8 vc0 = *(const half8*)&Vc[(l16) * 64 + c0];
        half8 vc1 = *(const half8*)&Vc[(l16) * 64 + c1];
#pragma unroll
        for (int sd = 0; sd < 4; sd++) {
            floatx4 o = ot[sd];
            o = MFMA16(vc0, pa[0], o);
            o = MFMA16(vc1, pa[1], o);
            if (sd < 3) {
                const int ro = ((sd + 1) * 16 + l16) * 64;
                vc0 = *(const half8*)&Vc[ro + c0];
                vc1 = *(const half8*)&Vc[ro + c1];
            }
            ot[sd] = o;
        }
        mmc = mmn;
        cur ^= 1;
    }

    // reduce l over the 4 qd-lanes holding the same m (lane bits 4,5)
    l_acc += __shfl_xor(l_acc, 16);
    l_acc += __shfl_xor(l_acc, 32);

    // store f32 partials (non-temporal)
    {
        size_t row = (size_t)(z * 32 + bh) * M_ + m_base + l16;
        float* op = Op + row * DH_ + qd * 4;
#pragma unroll
        for (int sd = 0; sd < 4; sd++)
            __builtin_nontemporal_store(ot[sd], (floatx4*)(op + sd * 16));
        if (qd == 0) __builtin_nontemporal_store(l_acc, Lp + row);
    }
}

// ---------------- combine splits: Ob = (sum Op) / (sum l), f16 (B*M, D), float4 ----------------
__global__ __launch_bounds__(256)
void comb_k(const float* __restrict__ Op, const float* __restrict__ Lp, f16* __restrict__ Ob,
            int nsp) {
    int i = blockIdx.x * 256 + threadIdx.x;   // B*M*D/4 = 524288 threads
    int d4 = i & 15, m = (i >> 4) & 1023, bh = i >> 14;
    float nx = 0.f, ny = 0.f, nz = 0.f, nw = 0.f, den = 0.f;
    for (int s = 0; s < nsp; s++) {
        size_t row = ((size_t)s * 32 + bh) * M_ + m;
        float4 x = *(const float4*)(Op + row * DH_ + d4 * 4);
        nx += x.x; ny += x.y; nz += x.z; nw += x.w;
        den += Lp[row];
    }
    float r = 1.0f / den;
    int b = bh >> 3, h = bh & 7;
    f16* o = Ob + ((size_t)(b * M_ + m)) * D_ + h * DH_ + d4 * 4;
    half4 hv; hv[0] = (f16)(nx * r); hv[1] = (f16)(ny * r); hv[2] = (f16)(nz * r); hv[3] = (f16)(nw * r);
    *(half4*)o = hv;
}

// ---------------- out-projection GEMM: 64x64 tiles, 2-phase double-buffered ----------------
__global__ __launch_bounds__(256)
void gemmout_k(const f16* __restrict__ A, const f16* __restrict__ Bt,
               float* __restrict__ Fout, const float* __restrict__ bias) {
    __shared__ __align__(16) f16 As[2][64 * 64];
    __shared__ __align__(16) f16 Bs[2][64 * 64];
    const int tid = threadIdx.x;
    const int lane = tid & 63, wave = tid >> 6;
    const int qd = lane >> 4, l16 = lane & 15;
    const int wm = wave >> 1, wn = wave & 1;
    const size_t m0 = (size_t)blockIdx.x * 64;
    const size_t n0 = (size_t)blockIdx.y * 64;

    size_t goff[2];
    f16 *la[2][2], *lb[2][2];
#pragma unroll
    for (int i = 0; i < 2; i++) {
        int c = i * 256 + wave * 64 + lane;
        int row = c >> 3, col8 = (c & 7) ^ (row & 7);
        goff[i] = (size_t)row * 512 + col8 * 8;
        la[0][i] = &As[0][(size_t)(i * 256 + wave * 64) * 8];
        la[1][i] = &As[1][(size_t)(i * 256 + wave * 64) * 8];
        lb[0][i] = &Bs[0][(size_t)(i * 256 + wave * 64) * 8];
        lb[1][i] = &Bs[1][(size_t)(i * 256 + wave * 64) * 8];
    }
    const f16* Ab = A + m0 * 512;
    const f16* Bb = Bt + n0 * 512;

    floatx4 acc[2][2] = {};

#pragma unroll
    for (int i = 0; i < 2; i++) g2lds16(Ab + goff[i], la[0][i]);
#pragma unroll
    for (int i = 0; i < 2; i++) g2lds16(Bb + goff[i], lb[0][i]);
    int cur = 0;

    for (int k0 = 0; k0 < 512; k0 += 64) {
        __syncthreads();
        if (k0 + 64 < 512) {
            const int nxt = cur ^ 1;
#pragma unroll
            for (int i = 0; i < 2; i++) g2lds16(Ab + goff[i] + k0 + 64, la[nxt][i]);
#pragma unroll
            for (int i = 0; i < 2; i++) g2lds16(Bb + goff[i] + k0 + 64, lb[nxt][i]);
        }
        const f16* Ac = &As[cur][0];
        const f16* Bc = &Bs[cur][0];
#pragma unroll
        for (int kk = 0; kk < 2; kk++) {
            half8 a[2], b[2];
#pragma unroll
            for (int t = 0; t < 2; t++) {
                int rowa = wm * 32 + t * 16 + l16;
                int rowb = wn * 32 + t * 16 + l16;
                int pa8 = ((kk * 4 + qd) ^ (rowa & 7)) * 8;
                int pb8 = ((kk * 4 + qd) ^ (rowb & 7)) * 8;
                a[t] = *(const half8*)&Ac[rowa * 64 + pa8];
                b[t] = *(const half8*)&Bc[rowb * 64 + pb8];
            }
#pragma unroll
            for (int mt = 0; mt < 2; mt++)
#pragma unroll
                for (int nt = 0; nt < 2; nt++)
                    acc[mt][nt] = MFMA16(a[mt], b[nt], acc[mt][nt]);
        }
        cur ^= 1;
    }

#pragma unroll
    for (int mt = 0; mt < 2; mt++)
#pragma unroll
        for (int nt = 0; nt < 2; nt++)
#pragma unroll
            for (int r = 0; r < 4; r++) {
                size_t row = m0 + wm * 32 + mt * 16 + qd * 4 + r;
                size_t col = n0 + wn * 32 + nt * 16 + l16;
                Fout[row * 512 + col] = acc[mt][nt][r] + bias[col];
            }
}

extern "C" void kernel_launch(void* const* d_in, const int* in_sizes, int n_in,
                              void* d_out, int out_size, void* d_ws, size_t ws_size,
                              hipStream_t stream) {
    const float* left  = (const float*)d_in[0];
    const float* right = (const float*)d_in[1];
    const void*  mask  = d_in[2];
    const float* Wq    = (const float*)d_in[3];
    const float* Wkv   = (const float*)d_in[4];
    const float* Wout  = (const float*)d_in[5];
    const float* bout  = (const float*)d_in[6];

    char* ws = (char*)d_ws;
    size_t off = 0;
    auto take = [&](size_t bytes) { char* p = ws + off; off += (bytes + 255) & ~(size_t)255; return p; };
    // ---- fixed allocations ----
    uint32* mbits = (uint32*)take((size_t)B_ * M_ * N_ / 8);           // 2 MB
    f16* woutt = (f16*)take((size_t)D_ * DQ_ * 2);                     // 0.5 MB
    f16* qb    = (f16*)take((size_t)B_ * M_ * D_ * 2);                 // 4 MB
    f16* kb    = (f16*)take((size_t)B_ * N_ * KP_ * 2);                // 18.9 MB (padded)
    f16* vt    = (f16*)take((size_t)B_ * H_ * DH_ * VP_ * 2);          // 17.3 MB (padded)
    f16* ob    = (f16*)take((size_t)B_ * M_ * D_ * 2);                 // 4 MB
    // ---- phase-overlay pool ----
    char* pool = (char*)take((size_t)34 * 1024 * 1024);
    f16* leftb  = (f16*)pool;
    f16* rightb = (f16*)(pool + (size_t)4 * 1024 * 1024);
    f16* wqt    = (f16*)(pool + (size_t)20 * 1024 * 1024);
    f16* wkvt   = (f16*)(pool + (size_t)21 * 1024 * 1024);
    float* Op   = (float*)pool;                                        // 32 MB
    float* Lp   = (float*)(pool + (size_t)NSPLIT * 32 * M_ * DH_ * 4); // 0.5 MB

    // 5 dispatches total
    prep_k<<<14592, 256, 0, stream>>>(mask, mbits, left, leftb, right, rightb,
                                      Wq, wqt, Wkv, wkvt, Wout, woutt);
    gemmqkv_k<<<1152, 256, 0, stream>>>(leftb, wqt, rightb, wkvt, qb, kb, vt);
    attn_k<<<dim3(32, 8, NSPLIT), 512, 0, stream>>>(qb, kb, vt, mbits, Op, Lp);
    comb_k<<<2048, 256, 0, stream>>>(Op, Lp, ob, NSPLIT);
    gemmout_k<<<dim3(64, 8), 256, 0, stream>>>(ob, woutt, (float*)d_out, bout);
}

// Round 7
// 273.635 us; speedup vs baseline: 1.0047x; 1.0047x over previous
//
#include <hip/hip_runtime.h>

typedef _Float16 f16;
typedef __attribute__((ext_vector_type(8))) _Float16 half8;
typedef __attribute__((ext_vector_type(4))) _Float16 half4;
typedef __attribute__((ext_vector_type(4))) float floatx4;
typedef unsigned int uint32;
typedef __attribute__((ext_vector_type(4))) uint32 uint4v;

#define MFMA16(a, b, c) __builtin_amdgcn_mfma_f32_16x16x32_f16((a), (b), (c), 0, 0, 0)

constexpr int B_ = 4, M_ = 1024, N_ = 4096, DQ_ = 512, DC_ = 512, H_ = 8, DH_ = 64, D_ = 512;
constexpr int KP_ = 576;       // K row stride (halves)
constexpr int VP_ = 4224;      // Vt row stride (halves)
constexpr int NSPLIT = 4;      // proven L2-coherent split
constexpr float QSC_ = 0.18033688011112042f;  // 0.125 * log2(e)

typedef __attribute__((address_space(1))) const void glds_g;
typedef __attribute__((address_space(3))) void glds_l;
__device__ __forceinline__ void g2lds16(const void* g, void* l) {
    __builtin_amdgcn_global_load_lds((glds_g*)g, (glds_l*)l, 16, 0, 0);
}

// ---- 64x64 f32->f16 transpose tile through LDS (device helper) ----
__device__ __forceinline__ void wtr_tile(const float* __restrict__ src, f16* __restrict__ dst,
                                         int Nout, int bx, int by, int tid) {
    __shared__ __align__(16) f16 Ts[64][72];
    const int n0 = bx * 64, k0 = by * 64;
    {
        int kr = tid >> 2, q4 = tid & 3;
        const float* sp = src + (size_t)(k0 + kr) * Nout + n0 + q4 * 16;
        float4 x0 = *(const float4*)(sp + 0), x1 = *(const float4*)(sp + 4);
        float4 x2 = *(const float4*)(sp + 8), x3 = *(const float4*)(sp + 12);
        half8 h0, h1;
        h0[0]=(f16)x0.x; h0[1]=(f16)x0.y; h0[2]=(f16)x0.z; h0[3]=(f16)x0.w;
        h0[4]=(f16)x1.x; h0[5]=(f16)x1.y; h0[6]=(f16)x1.z; h0[7]=(f16)x1.w;
        h1[0]=(f16)x2.x; h1[1]=(f16)x2.y; h1[2]=(f16)x2.z; h1[3]=(f16)x2.w;
        h1[4]=(f16)x3.x; h1[5]=(f16)x3.y; h1[6]=(f16)x3.z; h1[7]=(f16)x3.w;
        *(half8*)&Ts[kr][q4 * 16] = h0;
        *(half8*)&Ts[kr][q4 * 16 + 8] = h1;
    }
    __syncthreads();
    {
        int nr = tid >> 2, q = tid & 3;
        half8 h0, h1;
#pragma unroll
        for (int j = 0; j < 8; j++) { h0[j] = Ts[q * 16 + j][nr]; h1[j] = Ts[q * 16 + 8 + j][nr]; }
        f16* dp = dst + (size_t)(n0 + nr) * 512 + k0 + q * 16;
        *(half8*)(dp + 0) = h0;
        *(half8*)(dp + 8) = h1;
    }
}

// ---------------- prep mega-kernel ----------------
// mask region: single-round 16-elem/thread pack (uint4 loads + shfl merge).
__global__ __launch_bounds__(256)
void prep_k(const void* __restrict__ mask, uint32* __restrict__ bits,
            const float* __restrict__ left, f16* __restrict__ leftb,
            const float* __restrict__ right, f16* __restrict__ rightb,
            const float* __restrict__ Wq, f16* __restrict__ wqt,
            const float* __restrict__ Wkv, f16* __restrict__ wkvt,
            const float* __restrict__ Wout, f16* __restrict__ woutt) {
    const int blk = blockIdx.x, tid = threadIdx.x;
    if (blk < 4096) {
        // dtype detect on the block's OWN 4KB word-window (in-bounds both layouts)
        __shared__ int s_bad;
        if (tid == 0) s_bad = 0;
        __syncthreads();
        const uint32* w = (const uint32*)mask + (size_t)blk * 1024;
        int bad = 0;
#pragma unroll
        for (int j = 0; j < 4; j++) bad |= (w[tid * 4 + j] & 0xFFFFFFFEu) != 0u;
        if (bad) s_bad = 1;  // benign race: all writers store 1
        __syncthreads();
        const bool bytes_mode = s_bad != 0;
        // thread owns elems [blk*4096 + tid*16, +16)
        uint32 v = 0;
        if (bytes_mode) {
            uint4 x = *(const uint4*)((const unsigned char*)mask + (size_t)blk * 4096 + tid * 16);
            uint32 ws_[4] = {x.x, x.y, x.z, x.w};
#pragma unroll
            for (int k = 0; k < 4; k++)
#pragma unroll
                for (int bb = 0; bb < 4; bb++)
                    v |= (((ws_[k] >> (8 * bb)) & 0xFFu) != 0u ? 1u : 0u) << (k * 4 + bb);
        } else {
            const uint4* p = (const uint4*)((const uint32*)mask + (size_t)blk * 4096 + tid * 16);
            uint4 x0 = p[0], x1 = p[1], x2 = p[2], x3 = p[3];
            uint32 ws_[16] = {x0.x, x0.y, x0.z, x0.w, x1.x, x1.y, x1.z, x1.w,
                              x2.x, x2.y, x2.z, x2.w, x3.x, x3.y, x3.z, x3.w};
#pragma unroll
            for (int k = 0; k < 16; k++) v |= (ws_[k] != 0u ? 1u : 0u) << k;
        }
        uint32 other = (uint32)__shfl_xor((int)v, 1);
        if ((tid & 1) == 0)
            bits[(size_t)blk * 128 + (tid >> 1)] = v | (other << 16);
    } else if (blk < 6144) {
        int i = ((blk - 4096) * 256 + tid) * 4;
        float4 x = *(const float4*)(left + i);
        half4 h; h[0] = (f16)x.x; h[1] = (f16)x.y; h[2] = (f16)x.z; h[3] = (f16)x.w;
        *(half4*)(leftb + i) = h;
    } else if (blk < 14336) {
        int i = ((blk - 6144) * 256 + tid) * 4;
        float4 x = *(const float4*)(right + i);
        half4 h; h[0] = (f16)x.x; h[1] = (f16)x.y; h[2] = (f16)x.z; h[3] = (f16)x.w;
        *(half4*)(rightb + i) = h;
    } else if (blk < 14400) {
        int r = blk - 14336;
        wtr_tile(Wq, wqt, 512, r & 7, r >> 3, tid);
    } else if (blk < 14528) {
        int r = blk - 14400;
        wtr_tile(Wkv, wkvt, 1024, r & 15, r >> 4, tid);
    } else {
        int r = blk - 14528;
        wtr_tile(Wout, woutt, 512, r & 7, r >> 3, tid);
    }
}

// ---------------- fused q-proj + kv-proj GEMM (128x128, BK=64, xor-swizzled LDS) ------------
// XCD-chunked bijective remap: XCD x owns m-rows [16x,16x+16) x ALL n (L2 working set < 4MB).
__global__ __launch_bounds__(256)
void gemmqkv_k(const f16* __restrict__ leftb, const f16* __restrict__ wqt,
               const f16* __restrict__ rightb, const f16* __restrict__ wkvt,
               f16* __restrict__ qb, f16* __restrict__ kb, f16* __restrict__ vt) {
    __shared__ __align__(16) f16 As[128 * 64];
    __shared__ __align__(16) f16 Bs[128 * 64];
    const int hw = blockIdx.x, tid = threadIdx.x;
    const int lane = tid & 63, wave = tid >> 6;
    const int qd = lane >> 4, l16 = lane & 15;
    const int wm = wave >> 1, wn = wave & 1;

    // mode: 0 = K-half kv, 1 = V-half kv (swapped), 2 = q
    int mode;
    const f16* A; const f16* Bt; size_t m0, n0;
    if (hw < 1024) {
        const int xcd = hw & 7, slot = hw >> 3;
        const int mi_ = xcd * 16 + (slot & 15);
        const int ni_ = slot >> 4;
        size_t rows = (size_t)mi_ * 128, cols = (size_t)ni_ * 128;
        if (cols < 512) { mode = 0; A = rightb; m0 = rows; Bt = wkvt;   n0 = cols; }
        else            { mode = 1; A = wkvt;   m0 = cols; Bt = rightb; n0 = rows; }
    } else {
        const int r = hw - 1024;
        const int xcd = r & 7, slot = r >> 3;
        const int mi_ = xcd * 4 + (slot & 3);
        const int ni_ = slot >> 2;
        mode = 2; A = leftb; Bt = wqt;
        m0 = (size_t)mi_ * 128; n0 = (size_t)ni_ * 128;
    }

    size_t goff[4];
    f16 *la[4], *lb[4];
#pragma unroll
    for (int i = 0; i < 4; i++) {
        int c = i * 256 + wave * 64 + lane;
        int row = c >> 3, col8 = (c & 7) ^ (row & 7);
        goff[i] = (size_t)row * 512 + col8 * 8;
        la[i] = As + (size_t)(i * 256 + wave * 64) * 8;
        lb[i] = Bs + (size_t)(i * 256 + wave * 64) * 8;
    }
    const f16* Ab = A + m0 * 512;
    const f16* Bb = Bt + n0 * 512;

    floatx4 acc[4][4] = {};

    for (int k0 = 0; k0 < 512; k0 += 64) {
        __syncthreads();
#pragma unroll
        for (int i = 0; i < 4; i++) g2lds16(Ab + goff[i] + k0, la[i]);
#pragma unroll
        for (int i = 0; i < 4; i++) g2lds16(Bb + goff[i] + k0, lb[i]);
        __syncthreads();
#pragma unroll
        for (int kk = 0; kk < 2; kk++) {
            half8 a[4], b[4];
#pragma unroll
            for (int t = 0; t < 4; t++) {
                int rowa = wm * 64 + t * 16 + l16;
                int rowb = wn * 64 + t * 16 + l16;
                int pa8 = ((kk * 4 + qd) ^ (rowa & 7)) * 8;
                int pb8 = ((kk * 4 + qd) ^ (rowb & 7)) * 8;
                a[t] = *(const half8*)&As[rowa * 64 + pa8];
                b[t] = *(const half8*)&Bs[rowb * 64 + pb8];
            }
#pragma unroll
            for (int mt = 0; mt < 4; mt++)
#pragma unroll
                for (int nt = 0; nt < 4; nt++)
                    acc[mt][nt] = MFMA16(a[mt], b[nt], acc[mt][nt]);
        }
    }

#pragma unroll
    for (int mt = 0; mt < 4; mt++)
#pragma unroll
        for (int nt = 0; nt < 4; nt++)
#pragma unroll
            for (int r = 0; r < 4; r++) {
                size_t mi = m0 + wm * 64 + mt * 16 + qd * 4 + r;  // C/D row index
                size_t ni = n0 + wn * 64 + nt * 16 + l16;         // C/D col index
                float v = acc[mt][nt][r];
                if (mode == 2) {
                    qb[mi * 512 + ni] = (f16)v;
                } else if (mode == 0) {
                    kb[mi * KP_ + ni] = (f16)v;
                } else {
                    int dcol = (int)mi - 512;
                    int hh = dcol >> 6, dh = dcol & 63;
                    size_t bb = ni >> 12, nn = ni & 4095;
                    vt[((bb * H_ + hh) * (size_t)DH_ + dh) * VP_ + nn] = (f16)v;
                }
            }
}

// ---------------- flash attention v7: 8 waves x 32 rows (LDS reads amortized 2x) ------------
// v4 audit: 41 of 66.5us was LDS-read occupancy (all 8 waves read the SAME K/V tile).
// v7: each wave owns 32 m-rows (2 Q fragments) -> same 16 ds_reads feed 2x the MFMA output;
// per-CU LDS read cost per unit work halves. Block covers 256 rows; grid (32, 4, NSPLIT).
// launch_bounds(512,4): 128-VGPR cap fits the ~110-reg live set WITHOUT spill (v5/v6 lesson:
// the (512,8) 64-cap spills on any live-range growth -> FETCH/WRITE balloon tripwire).
// Body is v4's proven ordering, widened by f; no frag prefetch, no setprio.
__global__ __launch_bounds__(512, 4)
void attn_k(const f16* __restrict__ Qb, const f16* __restrict__ Kb,
            const f16* __restrict__ Vt, const uint32* __restrict__ mb,
            float* __restrict__ Op, float* __restrict__ Lp) {
    const int tid = threadIdx.x;
    const int lane = tid & 63, wave = tid >> 6;     // wave 0..7
    const int qd = lane >> 4, l16 = lane & 15;
    const int bh = blockIdx.x, b = bh >> 3, h = bh & 7;
    const int z = blockIdx.z;
    constexpr int iters = N_ / (64 * NSPLIT);   // 16
    const int n_base = z * iters * 64;
    const int m_base = blockIdx.y * 256 + wave * 32;

    __shared__ __align__(16) f16 Ks[2][64 * 64];   // [n][d] chunks, xor-swizzled
    __shared__ __align__(16) f16 Vs[2][64 * 64];   // [dh][n] chunks, xor-swizzled

    // Q B-operand fragments for 2x16 rows, pre-scaled by 0.125*log2(e)
    half8 q[2][2];
#pragma unroll
    for (int f = 0; f < 2; f++) {
        const f16* qrow = Qb + ((size_t)(b * M_ + m_base + f * 16 + l16)) * D_ + h * DH_;
        half8 r0 = *(const half8*)(qrow + qd * 8);
        half8 r1 = *(const half8*)(qrow + 32 + qd * 8);
#pragma unroll
        for (int j = 0; j < 8; j++) {
            q[f][0][j] = (f16)((float)r0[j] * QSC_);
            q[f][1][j] = (f16)((float)r1[j] * QSC_);
        }
    }

    floatx4 ot[2][4] = {};   // ot[f][sd][r] = O[m=f*16+l16][d=sd*16+qd*4+r]
    float la0 = 0.0f, la1 = 0.0f;

    const uint32* mrow0 = mb + ((size_t)(b * M_ + m_base + l16)) * (N_ / 32);
    const uint32* mrow1 = mrow0 + (size_t)16 * (N_ / 32);

    // staging: wave w owns 8 rows [8w, 8w+8), 1 g2lds16 each for K and V
    const int srow = wave * 8;
    const int r8 = lane >> 3, p8 = lane & 7;
    const int gc8 = p8 ^ r8;
    const f16* kg = Kb + ((size_t)(b * N_) + srow + r8) * KP_ + h * DH_ + gc8 * 8;
    const f16* vg = Vt + ((size_t)(bh * DH_) + srow + r8) * VP_ + gc8 * 8;

    auto stage = [&](int buf, int n0) {
        g2lds16(kg + (size_t)n0 * KP_, &Ks[buf][srow * 64]);
        g2lds16(vg + n0, &Vs[buf][srow * 64]);
    };

    stage(0, n_base);
    uint2 mc0 = *(const uint2*)(mrow0 + (n_base >> 5));
    uint2 mc1 = *(const uint2*)(mrow1 + (n_base >> 5));
    int cur = 0;

    const int swz = (l16 & 7);
    const int c0 = (qd ^ swz) * 8;
    const int c1 = ((4 + qd) ^ swz) * 8;

    for (int it = 0; it < iters; it++) {
        const int n0 = n_base + it * 64;
        __syncthreads();
        uint2 mn0, mn1;
        if (it + 1 < iters) {
            stage(cur ^ 1, n0 + 64);
            mn0 = *(const uint2*)(mrow0 + ((n0 + 64) >> 5));
            mn1 = *(const uint2*)(mrow1 + ((n0 + 64) >> 5));
        }
        const f16* Kc = &Ks[cur][0];
        const f16* Vc = &Vs[cur][0];

        const uint32 u00 = mc0.x >> (qd * 4), u01 = mc0.y >> (qd * 4);
        const uint32 u10 = mc1.x >> (qd * 4), u11 = mc1.y >> (qd * 4);

        // S^T = K·Q^T per 16-n subtile; mask; P = exp2; accumulate l; pack pairs (RTZ)
        uint32 pk[2][4][2];
#pragma unroll
        for (int s = 0; s < 4; s++) {
            const int ro = (s * 16 + l16) * 64;
            half8 k0 = *(const half8*)&Kc[ro + c0];
            half8 k1 = *(const half8*)&Kc[ro + c1];
            // f = 0
            {
                floatx4 t = {};
                t = MFMA16(k0, q[0][0], t);
                t = MFMA16(k1, q[0][1], t);
                uint32 us = (s & 2 ? u01 : u00) >> ((s & 1) * 16);
                float e0 = __builtin_amdgcn_exp2f(t[0]);
                float e1 = __builtin_amdgcn_exp2f(t[1]);
                float e2 = __builtin_amdgcn_exp2f(t[2]);
                float e3 = __builtin_amdgcn_exp2f(t[3]);
                e0 = (us & 1u) ? e0 : 0.0f;
                e1 = (us & 2u) ? e1 : 0.0f;
                e2 = (us & 4u) ? e2 : 0.0f;
                e3 = (us & 8u) ? e3 : 0.0f;
                la0 += (e0 + e1) + (e2 + e3);
                pk[0][s][0] = __builtin_bit_cast(uint32, __builtin_amdgcn_cvt_pkrtz(e0, e1));
                pk[0][s][1] = __builtin_bit_cast(uint32, __builtin_amdgcn_cvt_pkrtz(e2, e3));
            }
            // f = 1
            {
                floatx4 t = {};
                t = MFMA16(k0, q[1][0], t);
                t = MFMA16(k1, q[1][1], t);
                uint32 us = (s & 2 ? u11 : u10) >> ((s & 1) * 16);
                float e0 = __builtin_amdgcn_exp2f(t[0]);
                float e1 = __builtin_amdgcn_exp2f(t[1]);
                float e2 = __builtin_amdgcn_exp2f(t[2]);
                float e3 = __builtin_amdgcn_exp2f(t[3]);
                e0 = (us & 1u) ? e0 : 0.0f;
                e1 = (us & 2u) ? e1 : 0.0f;
                e2 = (us & 4u) ? e2 : 0.0f;
                e3 = (us & 8u) ? e3 : 0.0f;
                la1 += (e0 + e1) + (e2 + e3);
                pk[1][s][0] = __builtin_bit_cast(uint32, __builtin_amdgcn_cvt_pkrtz(e0, e1));
                pk[1][s][1] = __builtin_bit_cast(uint32, __builtin_amdgcn_cvt_pkrtz(e2, e3));
            }
        }

        // In-register routing: pa[f][hh] lane(qd,l16) elem j = P[m=f*16+l16][n=32hh+8qd+j]
        half8 pa[2][2];
#pragma unroll
        for (int f = 0; f < 2; f++)
#pragma unroll
            for (int hh = 0; hh < 2; hh++) {
                uint32 w0, w1, w2, w3;
                {
                    auto a = __builtin_amdgcn_permlane32_swap(pk[f][2 * hh][0], pk[f][2 * hh + 1][0], false, false);
                    auto c = __builtin_amdgcn_permlane16_swap(a[0], a[1], false, false);
                    w0 = c[0]; w2 = c[1];
                }
                {
                    auto a = __builtin_amdgcn_permlane32_swap(pk[f][2 * hh][1], pk[f][2 * hh + 1][1], false, false);
                    auto c = __builtin_amdgcn_permlane16_swap(a[0], a[1], false, false);
                    w1 = c[0]; w3 = c[1];
                }
                uint4v wv = {w0, w1, w2, w3};
                pa[f][hh] = __builtin_bit_cast(half8, wv);
            }

        // O^T += V^T @ P^T  (one V-frag pair feeds both f)
#pragma unroll
        for (int sd = 0; sd < 4; sd++) {
            const int ro = (sd * 16 + l16) * 64;
            half8 v0 = *(const half8*)&Vc[ro + c0];
            half8 v1 = *(const half8*)&Vc[ro + c1];
            ot[0][sd] = MFMA16(v0, pa[0][0], ot[0][sd]);
            ot[0][sd] = MFMA16(v1, pa[0][1], ot[0][sd]);
            ot[1][sd] = MFMA16(v0, pa[1][0], ot[1][sd]);
            ot[1][sd] = MFMA16(v1, pa[1][1], ot[1][sd]);
        }
        mc0 = mn0; mc1 = mn1;
        cur ^= 1;
    }

    // reduce l over the 4 qd-lanes holding the same m (lane bits 4,5)
    la0 += __shfl_xor(la0, 16);
    la0 += __shfl_xor(la0, 32);
    la1 += __shfl_xor(la1, 16);
    la1 += __shfl_xor(la1, 32);

    // store f32 partials (non-temporal: don't evict K/V from L2)
#pragma unroll
    for (int f = 0; f < 2; f++) {
        size_t row = (size_t)(z * 32 + bh) * M_ + m_base + f * 16 + l16;
        float* op = Op + row * DH_ + qd * 4;
#pragma unroll
        for (int sd = 0; sd < 4; sd++)
            __builtin_nontemporal_store(ot[f][sd], (floatx4*)(op + sd * 16));
        if (qd == 0) __builtin_nontemporal_store(f == 0 ? la0 : la1, Lp + row);
    }
}

// ---------------- combine splits: Ob = (sum Op) / (sum l), f16 (B*M, D), float4 ----------------
__global__ __launch_bounds__(256)
void comb_k(const float* __restrict__ Op, const float* __restrict__ Lp, f16* __restrict__ Ob,
            int nsp) {
    int i = blockIdx.x * 256 + threadIdx.x;   // B*M*D/4 = 524288 threads
    int d4 = i & 15, m = (i >> 4) & 1023, bh = i >> 14;
    float nx = 0.f, ny = 0.f, nz = 0.f, nw = 0.f, den = 0.f;
    for (int s = 0; s < nsp; s++) {
        size_t row = ((size_t)s * 32 + bh) * M_ + m;
        float4 x = *(const float4*)(Op + row * DH_ + d4 * 4);
        nx += x.x; ny += x.y; nz += x.z; nw += x.w;
        den += Lp[row];
    }
    float r = 1.0f / den;
    int b = bh >> 3, h = bh & 7;
    f16* o = Ob + ((size_t)(b * M_ + m)) * D_ + h * DH_ + d4 * 4;
    half4 hv; hv[0] = (f16)(nx * r); hv[1] = (f16)(ny * r); hv[2] = (f16)(nz * r); hv[3] = (f16)(nw * r);
    *(half4*)o = hv;
}

// ---------------- out-projection GEMM: 64x64 tiles, 2-phase double-buffered ----------------
__global__ __launch_bounds__(256)
void gemmout_k(const f16* __restrict__ A, const f16* __restrict__ Bt,
               float* __restrict__ Fout, const float* __restrict__ bias) {
    __shared__ __align__(16) f16 As[2][64 * 64];
    __shared__ __align__(16) f16 Bs[2][64 * 64];
    const int tid = threadIdx.x;
    const int lane = tid & 63, wave = tid >> 6;
    const int qd = lane >> 4, l16 = lane & 15;
    const int wm = wave >> 1, wn = wave & 1;
    const size_t m0 = (size_t)blockIdx.x * 64;
    const size_t n0 = (size_t)blockIdx.y * 64;

    size_t goff[2];
    f16 *la[2][2], *lb[2][2];
#pragma unroll
    for (int i = 0; i < 2; i++) {
        int c = i * 256 + wave * 64 + lane;
        int row = c >> 3, col8 = (c & 7) ^ (row & 7);
        goff[i] = (size_t)row * 512 + col8 * 8;
        la[0][i] = &As[0][(size_t)(i * 256 + wave * 64) * 8];
        la[1][i] = &As[1][(size_t)(i * 256 + wave * 64) * 8];
        lb[0][i] = &Bs[0][(size_t)(i * 256 + wave * 64) * 8];
        lb[1][i] = &Bs[1][(size_t)(i * 256 + wave * 64) * 8];
    }
    const f16* Ab = A + m0 * 512;
    const f16* Bb = Bt + n0 * 512;

    floatx4 acc[2][2] = {};

#pragma unroll
    for (int i = 0; i < 2; i++) g2lds16(Ab + goff[i], la[0][i]);
#pragma unroll
    for (int i = 0; i < 2; i++) g2lds16(Bb + goff[i], lb[0][i]);
    int cur = 0;

    for (int k0 = 0; k0 < 512; k0 += 64) {
        __syncthreads();
        if (k0 + 64 < 512) {
            const int nxt = cur ^ 1;
#pragma unroll
            for (int i = 0; i < 2; i++) g2lds16(Ab + goff[i] + k0 + 64, la[nxt][i]);
#pragma unroll
            for (int i = 0; i < 2; i++) g2lds16(Bb + goff[i] + k0 + 64, lb[nxt][i]);
        }
        const f16* Ac = &As[cur][0];
        const f16* Bc = &Bs[cur][0];
#pragma unroll
        for (int kk = 0; kk < 2; kk++) {
            half8 a[2], b[2];
#pragma unroll
            for (int t = 0; t < 2; t++) {
                int rowa = wm * 32 + t * 16 + l16;
                int rowb = wn * 32 + t * 16 + l16;
                int pa8 = ((kk * 4 + qd) ^ (rowa & 7)) * 8;
                int pb8 = ((kk * 4 + qd) ^ (rowb & 7)) * 8;
                a[t] = *(const half8*)&Ac[rowa * 64 + pa8];
                b[t] = *(const half8*)&Bc[rowb * 64 + pb8];
            }
#pragma unroll
            for (int mt = 0; mt < 2; mt++)
#pragma unroll
                for (int nt = 0; nt < 2; nt++)
                    acc[mt][nt] = MFMA16(a[mt], b[nt], acc[mt][nt]);
        }
        cur ^= 1;
    }

#pragma unroll
    for (int mt = 0; mt < 2; mt++)
#pragma unroll
        for (int nt = 0; nt < 2; nt++)
#pragma unroll
            for (int r = 0; r < 4; r++) {
                size_t row = m0 + wm * 32 + mt * 16 + qd * 4 + r;
                size_t col = n0 + wn * 32 + nt * 16 + l16;
                Fout[row * 512 + col] = acc[mt][nt][r] + bias[col];
            }
}

extern "C" void kernel_launch(void* const* d_in, const int* in_sizes, int n_in,
                              void* d_out, int out_size, void* d_ws, size_t ws_size,
                              hipStream_t stream) {
    const float* left  = (const float*)d_in[0];
    const float* right = (const float*)d_in[1];
    const void*  mask  = d_in[2];
    const float* Wq    = (const float*)d_in[3];
    const float* Wkv   = (const float*)d_in[4];
    const float* Wout  = (const float*)d_in[5];
    const float* bout  = (const float*)d_in[6];

    char* ws = (char*)d_ws;
    size_t off = 0;
    auto take = [&](size_t bytes) { char* p = ws + off; off += (bytes + 255) & ~(size_t)255; return p; };
    // ---- fixed allocations ----
    uint32* mbits = (uint32*)take((size_t)B_ * M_ * N_ / 8);           // 2 MB
    f16* woutt = (f16*)take((size_t)D_ * DQ_ * 2);                     // 0.5 MB
    f16* qb    = (f16*)take((size_t)B_ * M_ * D_ * 2);                 // 4 MB
    f16* kb    = (f16*)take((size_t)B_ * N_ * KP_ * 2);                // 18.9 MB (padded)
    f16* vt    = (f16*)take((size_t)B_ * H_ * DH_ * VP_ * 2);          // 17.3 MB (padded)
    f16* ob    = (f16*)take((size_t)B_ * M_ * D_ * 2);                 // 4 MB
    // ---- phase-overlay pool ----
    char* pool = (char*)take((size_t)34 * 1024 * 1024);
    f16* leftb  = (f16*)pool;
    f16* rightb = (f16*)(pool + (size_t)4 * 1024 * 1024);
    f16* wqt    = (f16*)(pool + (size_t)20 * 1024 * 1024);
    f16* wkvt   = (f16*)(pool + (size_t)21 * 1024 * 1024);
    float* Op   = (float*)pool;                                        // 32 MB
    float* Lp   = (float*)(pool + (size_t)NSPLIT * 32 * M_ * DH_ * 4); // 0.5 MB

    // 5 dispatches total
    prep_k<<<14592, 256, 0, stream>>>(mask, mbits, left, leftb, right, rightb,
                                      Wq, wqt, Wkv, wkvt, Wout, woutt);
    gemmqkv_k<<<1152, 256, 0, stream>>>(leftb, wqt, rightb, wkvt, qb, kb, vt);
    attn_k<<<dim3(32, 4, NSPLIT), 512, 0, stream>>>(qb, kb, vt, mbits, Op, Lp);
    comb_k<<<2048, 256, 0, stream>>>(Op, Lp, ob, NSPLIT);
    gemmout_k<<<dim3(64, 8), 256, 0, stream>>>(ob, woutt, (float*)d_out, bout);
}

// Round 8
// 266.546 us; speedup vs baseline: 1.0314x; 1.0266x over previous
//
#include <hip/hip_runtime.h>

typedef _Float16 f16;
typedef __attribute__((ext_vector_type(8))) _Float16 half8;
typedef __attribute__((ext_vector_type(4))) _Float16 half4;
typedef __attribute__((ext_vector_type(4))) float floatx4;
typedef unsigned int uint32;
typedef __attribute__((ext_vector_type(4))) uint32 uint4v;

#define MFMA16(a, b, c) __builtin_amdgcn_mfma_f32_16x16x32_f16((a), (b), (c), 0, 0, 0)

constexpr int B_ = 4, M_ = 1024, N_ = 4096, DQ_ = 512, DC_ = 512, H_ = 8, DH_ = 64, D_ = 512;
constexpr int KP_ = 576;       // K row stride (halves)
constexpr int VP_ = 4224;      // Vt row stride (halves)
constexpr int NSPLIT = 4;      // proven L2-coherent split
constexpr float QSC_ = 0.18033688011112042f;  // 0.125 * log2(e)

typedef __attribute__((address_space(1))) const void glds_g;
typedef __attribute__((address_space(3))) void glds_l;
__device__ __forceinline__ void g2lds16(const void* g, void* l) {
    __builtin_amdgcn_global_load_lds((glds_g*)g, (glds_l*)l, 16, 0, 0);
}

// ---- 64x64 f32->f16 transpose tile through LDS (device helper) ----
__device__ __forceinline__ void wtr_tile(const float* __restrict__ src, f16* __restrict__ dst,
                                         int Nout, int bx, int by, int tid) {
    __shared__ __align__(16) f16 Ts[64][72];
    const int n0 = bx * 64, k0 = by * 64;
    {
        int kr = tid >> 2, q4 = tid & 3;
        const float* sp = src + (size_t)(k0 + kr) * Nout + n0 + q4 * 16;
        float4 x0 = *(const float4*)(sp + 0), x1 = *(const float4*)(sp + 4);
        float4 x2 = *(const float4*)(sp + 8), x3 = *(const float4*)(sp + 12);
        half8 h0, h1;
        h0[0]=(f16)x0.x; h0[1]=(f16)x0.y; h0[2]=(f16)x0.z; h0[3]=(f16)x0.w;
        h0[4]=(f16)x1.x; h0[5]=(f16)x1.y; h0[6]=(f16)x1.z; h0[7]=(f16)x1.w;
        h1[0]=(f16)x2.x; h1[1]=(f16)x2.y; h1[2]=(f16)x2.z; h1[3]=(f16)x2.w;
        h1[4]=(f16)x3.x; h1[5]=(f16)x3.y; h1[6]=(f16)x3.z; h1[7]=(f16)x3.w;
        *(half8*)&Ts[kr][q4 * 16] = h0;
        *(half8*)&Ts[kr][q4 * 16 + 8] = h1;
    }
    __syncthreads();
    {
        int nr = tid >> 2, q = tid & 3;
        half8 h0, h1;
#pragma unroll
        for (int j = 0; j < 8; j++) { h0[j] = Ts[q * 16 + j][nr]; h1[j] = Ts[q * 16 + 8 + j][nr]; }
        f16* dp = dst + (size_t)(n0 + nr) * 512 + k0 + q * 16;
        *(half8*)(dp + 0) = h0;
        *(half8*)(dp + 8) = h1;
    }
}

// ---------------- prep: mask-pack + weight transposes only (casts fused into gemmqkv) --------
// regions: [0,4096) mask-pack | [4096,4160) wtr Wq | [4160,4288) wtr Wkv | [4288,4352) wtr Wout
__global__ __launch_bounds__(256)
void prep_k(const void* __restrict__ mask, uint32* __restrict__ bits,
            const float* __restrict__ Wq, f16* __restrict__ wqt,
            const float* __restrict__ Wkv, f16* __restrict__ wkvt,
            const float* __restrict__ Wout, f16* __restrict__ woutt) {
    const int blk = blockIdx.x, tid = threadIdx.x;
    if (blk < 4096) {
        // dtype detect on the block's OWN 4KB word-window (in-bounds both layouts)
        __shared__ int s_bad;
        if (tid == 0) s_bad = 0;
        __syncthreads();
        const uint32* w = (const uint32*)mask + (size_t)blk * 1024;
        int bad = 0;
#pragma unroll
        for (int j = 0; j < 4; j++) bad |= (w[tid * 4 + j] & 0xFFFFFFFEu) != 0u;
        if (bad) s_bad = 1;  // benign race: all writers store 1
        __syncthreads();
        const bool bytes_mode = s_bad != 0;
        // thread owns elems [blk*4096 + tid*16, +16)
        uint32 v = 0;
        if (bytes_mode) {
            uint4 x = *(const uint4*)((const unsigned char*)mask + (size_t)blk * 4096 + tid * 16);
            uint32 ws_[4] = {x.x, x.y, x.z, x.w};
#pragma unroll
            for (int k = 0; k < 4; k++)
#pragma unroll
                for (int bb = 0; bb < 4; bb++)
                    v |= (((ws_[k] >> (8 * bb)) & 0xFFu) != 0u ? 1u : 0u) << (k * 4 + bb);
        } else {
            const uint4* p = (const uint4*)((const uint32*)mask + (size_t)blk * 4096 + tid * 16);
            uint4 x0 = p[0], x1 = p[1], x2 = p[2], x3 = p[3];
            uint32 ws_[16] = {x0.x, x0.y, x0.z, x0.w, x1.x, x1.y, x1.z, x1.w,
                              x2.x, x2.y, x2.z, x2.w, x3.x, x3.y, x3.z, x3.w};
#pragma unroll
            for (int k = 0; k < 16; k++) v |= (ws_[k] != 0u ? 1u : 0u) << k;
        }
        uint32 other = (uint32)__shfl_xor((int)v, 1);
        if ((tid & 1) == 0)
            bits[(size_t)blk * 128 + (tid >> 1)] = v | (other << 16);
    } else if (blk < 4160) {
        int r = blk - 4096;
        wtr_tile(Wq, wqt, 512, r & 7, r >> 3, tid);
    } else if (blk < 4288) {
        int r = blk - 4160;
        wtr_tile(Wkv, wkvt, 1024, r & 15, r >> 4, tid);
    } else {
        int r = blk - 4288;
        wtr_tile(Wout, woutt, 512, r & 7, r >> 3, tid);
    }
}

// ---------------- fused cast + q-proj + kv-proj GEMM (128x128, BK=64, xor-swizzled LDS) ------
// Reads left/right directly in f32: the f32-side operand is reg-staged (float4 loads -> RNE
// cast -> ds_write_b128 at the same swizzled layout); the f16 weight side keeps g2lds16.
// Next K-step's f32 loads issue at the start of compute (latency hides under 32 MFMAs).
// XCD remap (xcd = blk%8): XCD owns 8 m-panels x 8 n (2 m-groups): 2MB f32 A + 1MB B < 4MB L2.
__global__ __launch_bounds__(256)
void gemmqkv_k(const float* __restrict__ left, const f16* __restrict__ wqt,
               const float* __restrict__ right, const f16* __restrict__ wkvt,
               f16* __restrict__ qb, f16* __restrict__ kb, f16* __restrict__ vt) {
    __shared__ __align__(16) f16 As[128 * 64];
    __shared__ __align__(16) f16 Bs[128 * 64];
    const int hw = blockIdx.x, tid = threadIdx.x;
    const int lane = tid & 63, wave = tid >> 6;
    const int qd = lane >> 4, l16 = lane & 15;
    const int wm = wave >> 1, wn = wave & 1;

    // mode: 0 = K-half kv, 1 = V-half kv (swapped), 2 = q
    int mode;
    const float* F32b; const f16* F16b; size_t m0, n0;
    bool f32A;
    if (hw < 1024) {
        const int xcd = hw & 7, s = hw >> 3;               // s 0..127
        const int mi_ = (s >> 6) * 64 + xcd * 8 + (s & 7); // 0..127
        const int ni_ = (s >> 3) & 7;                      // 0..7
        size_t rows = (size_t)mi_ * 128, cols = (size_t)ni_ * 128;
        F32b = right + rows * 512;
        F16b = wkvt + cols * 512;
        if (cols < 512) { mode = 0; f32A = true;  m0 = rows; n0 = cols; }
        else            { mode = 1; f32A = false; m0 = cols; n0 = rows; }
    } else {
        const int r = hw - 1024;
        const int xcd = r & 7, s = r >> 3;                 // s 0..15
        const int mi_ = xcd * 4 + (s & 3);                 // 0..31
        const int ni_ = s >> 2;                            // 0..3
        mode = 2; f32A = true;
        m0 = (size_t)mi_ * 128; n0 = (size_t)ni_ * 128;
        F32b = left + m0 * 512;
        F16b = wqt + n0 * 512;
    }
    f16* LF32 = f32A ? As : Bs;   // LDS side receiving the f32-cast operand
    f16* LF16 = f32A ? Bs : As;

    // chunk geometry: chunk c = i*256 + tid -> row = c>>3, lds pos8 = c&7,
    // source col8 = (c&7) ^ (row&7)  (same swizzle both sides).
    int crow[4], ccol8[4];
    size_t g16off[4];
    f16* g16dst[4];
#pragma unroll
    for (int i = 0; i < 4; i++) {
        int c = i * 256 + wave * 64 + lane;
        int row = c >> 3, col8 = (c & 7) ^ (row & 7);
        crow[i] = row; ccol8[i] = col8;
        g16off[i] = (size_t)row * 512 + col8 * 8;
        g16dst[i] = LF16 + (size_t)(i * 256 + wave * 64) * 8;
    }

    floatx4 acc[4][4] = {};
    float4 ra[4][2];

    // prologue: f32 loads for k0 = 0
#pragma unroll
    for (int i = 0; i < 4; i++) {
        const float* sp = F32b + (size_t)crow[i] * 512 + ccol8[i] * 8;
        ra[i][0] = *(const float4*)sp;
        ra[i][1] = *(const float4*)(sp + 4);
    }

    for (int k0 = 0; k0 < 512; k0 += 64) {
        __syncthreads();   // ends prior compute's LDS reads (and drains in-flight vmem)
        // stage f16 side async + write f32-cast side from regs
#pragma unroll
        for (int i = 0; i < 4; i++) g2lds16(F16b + g16off[i] + k0, g16dst[i]);
#pragma unroll
        for (int i = 0; i < 4; i++) {
            half8 hh;
            hh[0] = (f16)ra[i][0].x; hh[1] = (f16)ra[i][0].y;
            hh[2] = (f16)ra[i][0].z; hh[3] = (f16)ra[i][0].w;
            hh[4] = (f16)ra[i][1].x; hh[5] = (f16)ra[i][1].y;
            hh[6] = (f16)ra[i][1].z; hh[7] = (f16)ra[i][1].w;
            *(half8*)&LF32[(size_t)(i * 256 + wave * 64 + lane) * 8] = hh;
        }
        __syncthreads();   // drains g2lds + ds_writes
        // issue next K-step's f32 loads now: latency hides under the MFMA phase
        if (k0 + 64 < 512) {
#pragma unroll
            for (int i = 0; i < 4; i++) {
                const float* sp = F32b + (size_t)crow[i] * 512 + (k0 + 64) + ccol8[i] * 8;
                ra[i][0] = *(const float4*)sp;
                ra[i][1] = *(const float4*)(sp + 4);
            }
        }
#pragma unroll
        for (int kk = 0; kk < 2; kk++) {
            half8 a[4], b[4];
#pragma unroll
            for (int t = 0; t < 4; t++) {
                int rowa = wm * 64 + t * 16 + l16;
                int rowb = wn * 64 + t * 16 + l16;
                int pa8 = ((kk * 4 + qd) ^ (rowa & 7)) * 8;
                int pb8 = ((kk * 4 + qd) ^ (rowb & 7)) * 8;
                a[t] = *(const half8*)&As[rowa * 64 + pa8];
                b[t] = *(const half8*)&Bs[rowb * 64 + pb8];
            }
#pragma unroll
            for (int mt = 0; mt < 4; mt++)
#pragma unroll
                for (int nt = 0; nt < 4; nt++)
                    acc[mt][nt] = MFMA16(a[mt], b[nt], acc[mt][nt]);
        }
    }

#pragma unroll
    for (int mt = 0; mt < 4; mt++)
#pragma unroll
        for (int nt = 0; nt < 4; nt++)
#pragma unroll
            for (int r = 0; r < 4; r++) {
                size_t mi = m0 + wm * 64 + mt * 16 + qd * 4 + r;  // C/D row index
                size_t ni = n0 + wn * 64 + nt * 16 + l16;         // C/D col index
                float v = acc[mt][nt][r];
                if (mode == 2) {
                    qb[mi * 512 + ni] = (f16)v;
                } else if (mode == 0) {
                    kb[mi * KP_ + ni] = (f16)v;
                } else {
                    int dcol = (int)mi - 512;
                    int hh = dcol >> 6, dh = dcol & 63;
                    size_t bb = ni >> 12, nn = ni & 4095;
                    vt[((bb * H_ + hh) * (size_t)DH_ + dh) * VP_ + nn] = (f16)v;
                }
            }
}

// ---------------- flash attention v4 (proven 66.5us): 8 thin waves, dbuf staging -------------
// Measured optimum across v4-v7: thin waves (16 rows) + max TLP beats ILP/prefetch/fat-wave
// variants (v5/v6 spilled under the (512,8) 64-VGPR cap; v7 halved wave count for -9%).
__global__ __launch_bounds__(512, 8)
void attn_k(const f16* __restrict__ Qb, const f16* __restrict__ Kb,
            const f16* __restrict__ Vt, const uint32* __restrict__ mb,
            float* __restrict__ Op, float* __restrict__ Lp) {
    const int tid = threadIdx.x;
    const int lane = tid & 63, wave = tid >> 6;     // wave 0..7
    const int qd = lane >> 4, l16 = lane & 15;
    const int bh = blockIdx.x, b = bh >> 3, h = bh & 7;
    const int z = blockIdx.z;
    constexpr int iters = N_ / (64 * NSPLIT);   // 16
    const int n_base = z * iters * 64;
    const int m_base = blockIdx.y * 128 + wave * 16;

    __shared__ __align__(16) f16 Ks[2][64 * 64];   // [n][d] chunks, xor-swizzled
    __shared__ __align__(16) f16 Vs[2][64 * 64];   // [dh][n] chunks, xor-swizzled

    // Q B-operand fragments for this wave's 16 rows, pre-scaled by 0.125*log2(e)
    half8 q0, q1;
    {
        const f16* qrow = Qb + ((size_t)(b * M_ + m_base + l16)) * D_ + h * DH_;
        half8 r0 = *(const half8*)(qrow + qd * 8);
        half8 r1 = *(const half8*)(qrow + 32 + qd * 8);
#pragma unroll
        for (int j = 0; j < 8; j++) {
            q0[j] = (f16)((float)r0[j] * QSC_);
            q1[j] = (f16)((float)r1[j] * QSC_);
        }
    }

    floatx4 ot[4] = {};   // O^T: ot[sd][r] = O[m=l16][d = sd*16+qd*4+r]
    float l_acc = 0.0f;   // partial softmax denom for m=l16 over this lane's n subset

    // mask row for m = l16
    const uint32* mrow = mb + ((size_t)(b * M_ + m_base + l16)) * (N_ / 32);

    // staging: wave w owns 8 rows [8w, 8w+8) of each tile, 1 g2lds16 each for K and V.
    const int srow = wave * 8;
    const int r8 = lane >> 3, p8 = lane & 7;
    const int gc8 = p8 ^ r8;
    const f16* kg = Kb + ((size_t)(b * N_) + srow + r8) * KP_ + h * DH_ + gc8 * 8;
    const f16* vg = Vt + ((size_t)(bh * DH_) + srow + r8) * VP_ + gc8 * 8;

    auto stage = [&](int buf, int n0) {
        g2lds16(kg + (size_t)n0 * KP_, &Ks[buf][srow * 64]);
        g2lds16(vg + n0, &Vs[buf][srow * 64]);
    };

    stage(0, n_base);
    uint2 mmc = *(const uint2*)(mrow + (n_base >> 5));
    int cur = 0;

    const int swz = (l16 & 7);   // read-side xor base

    for (int it = 0; it < iters; it++) {
        const int n0 = n_base + it * 64;
        __syncthreads();
        uint2 mmn;
        if (it + 1 < iters) {
            stage(cur ^ 1, n0 + 64);
            mmn = *(const uint2*)(mrow + ((n0 + 64) >> 5));
        }

        const uint32 u0 = mmc.x >> (qd * 4);
        const uint32 u1 = mmc.y >> (qd * 4);

        // S^T = K·Q^T per 16-n subtile; mask; P = exp2; accumulate l; pack pairs (RTZ)
        uint32 pk[4][2];
#pragma unroll
        for (int s = 0; s < 4; s++) {
            const int ro = (s * 16 + l16) * 64;
            half8 k0 = *(const half8*)&Ks[cur][ro + ((qd ^ swz) * 8)];
            half8 k1 = *(const half8*)&Ks[cur][ro + (((4 + qd) ^ swz) * 8)];
            floatx4 t = {};
            t = MFMA16(k0, q0, t);
            t = MFMA16(k1, q1, t);
            uint32 us = (s & 2 ? u1 : u0) >> ((s & 1) * 16);
            float e0 = __builtin_amdgcn_exp2f(t[0]);
            float e1 = __builtin_amdgcn_exp2f(t[1]);
            float e2 = __builtin_amdgcn_exp2f(t[2]);
            float e3 = __builtin_amdgcn_exp2f(t[3]);
            e0 = (us & 1u) ? e0 : 0.0f;
            e1 = (us & 2u) ? e1 : 0.0f;
            e2 = (us & 4u) ? e2 : 0.0f;
            e3 = (us & 8u) ? e3 : 0.0f;
            l_acc += (e0 + e1) + (e2 + e3);
            pk[s][0] = __builtin_bit_cast(uint32, __builtin_amdgcn_cvt_pkrtz(e0, e1));
            pk[s][1] = __builtin_bit_cast(uint32, __builtin_amdgcn_cvt_pkrtz(e2, e3));
        }

        // In-register routing: pa[hh] lane(qd,l16) elem j = P[m=l16][n=32hh+8qd+j]
        half8 pa[2];
#pragma unroll
        for (int hh = 0; hh < 2; hh++) {
            uint32 w0, w1, w2, w3;
            {
                auto a = __builtin_amdgcn_permlane32_swap(pk[2 * hh][0], pk[2 * hh + 1][0], false, false);
                auto c = __builtin_amdgcn_permlane16_swap(a[0], a[1], false, false);
                w0 = c[0]; w2 = c[1];
            }
            {
                auto a = __builtin_amdgcn_permlane32_swap(pk[2 * hh][1], pk[2 * hh + 1][1], false, false);
                auto c = __builtin_amdgcn_permlane16_swap(a[0], a[1], false, false);
                w1 = c[0]; w3 = c[1];
            }
            uint4v wv = {w0, w1, w2, w3};
            pa[hh] = __builtin_bit_cast(half8, wv);
        }

        // O^T += V^T @ P^T
#pragma unroll
        for (int sd = 0; sd < 4; sd++) {
            const int ro = (sd * 16 + l16) * 64;
            half8 v0 = *(const half8*)&Vs[cur][ro + ((qd ^ swz) * 8)];
            half8 v1 = *(const half8*)&Vs[cur][ro + (((4 + qd) ^ swz) * 8)];
            ot[sd] = MFMA16(v0, pa[0], ot[sd]);
            ot[sd] = MFMA16(v1, pa[1], ot[sd]);
        }
        mmc = mmn;
        cur ^= 1;
    }

    // reduce l over the 4 qd-lanes holding the same m (lane bits 4,5)
    l_acc += __shfl_xor(l_acc, 16);
    l_acc += __shfl_xor(l_acc, 32);

    // store f32 partials (non-temporal: don't evict K/V from L2)
    {
        size_t row = (size_t)(z * 32 + bh) * M_ + m_base + l16;
        float* op = Op + row * DH_ + qd * 4;
#pragma unroll
        for (int sd = 0; sd < 4; sd++)
            __builtin_nontemporal_store(ot[sd], (floatx4*)(op + sd * 16));
        if (qd == 0) __builtin_nontemporal_store(l_acc, Lp + row);
    }
}

// ---------------- combine splits: Ob = (sum Op) / (sum l), f16 (B*M, D), float4 ----------------
__global__ __launch_bounds__(256)
void comb_k(const float* __restrict__ Op, const float* __restrict__ Lp, f16* __restrict__ Ob,
            int nsp) {
    int i = blockIdx.x * 256 + threadIdx.x;   // B*M*D/4 = 524288 threads
    int d4 = i & 15, m = (i >> 4) & 1023, bh = i >> 14;
    float nx = 0.f, ny = 0.f, nz = 0.f, nw = 0.f, den = 0.f;
    for (int s = 0; s < nsp; s++) {
        size_t row = ((size_t)s * 32 + bh) * M_ + m;
        float4 x = *(const float4*)(Op + row * DH_ + d4 * 4);
        nx += x.x; ny += x.y; nz += x.z; nw += x.w;
        den += Lp[row];
    }
    float r = 1.0f / den;
    int b = bh >> 3, h = bh & 7;
    f16* o = Ob + ((size_t)(b * M_ + m)) * D_ + h * DH_ + d4 * 4;
    half4 hv; hv[0] = (f16)(nx * r); hv[1] = (f16)(ny * r); hv[2] = (f16)(nz * r); hv[3] = (f16)(nw * r);
    *(half4*)o = hv;
}

// ---------------- out-projection GEMM: 64x64 tiles, 2-phase double-buffered ----------------
__global__ __launch_bounds__(256)
void gemmout_k(const f16* __restrict__ A, const f16* __restrict__ Bt,
               float* __restrict__ Fout, const float* __restrict__ bias) {
    __shared__ __align__(16) f16 As[2][64 * 64];
    __shared__ __align__(16) f16 Bs[2][64 * 64];
    const int tid = threadIdx.x;
    const int lane = tid & 63, wave = tid >> 6;
    const int qd = lane >> 4, l16 = lane & 15;
    const int wm = wave >> 1, wn = wave & 1;
    const size_t m0 = (size_t)blockIdx.x * 64;
    const size_t n0 = (size_t)blockIdx.y * 64;

    size_t goff[2];
    f16 *la[2][2], *lb[2][2];
#pragma unroll
    for (int i = 0; i < 2; i++) {
        int c = i * 256 + wave * 64 + lane;
        int row = c >> 3, col8 = (c & 7) ^ (row & 7);
        goff[i] = (size_t)row * 512 + col8 * 8;
        la[0][i] = &As[0][(size_t)(i * 256 + wave * 64) * 8];
        la[1][i] = &As[1][(size_t)(i * 256 + wave * 64) * 8];
        lb[0][i] = &Bs[0][(size_t)(i * 256 + wave * 64) * 8];
        lb[1][i] = &Bs[1][(size_t)(i * 256 + wave * 64) * 8];
    }
    const f16* Ab = A + m0 * 512;
    const f16* Bb = Bt + n0 * 512;

    floatx4 acc[2][2] = {};

#pragma unroll
    for (int i = 0; i < 2; i++) g2lds16(Ab + goff[i], la[0][i]);
#pragma unroll
    for (int i = 0; i < 2; i++) g2lds16(Bb + goff[i], lb[0][i]);
    int cur = 0;

    for (int k0 = 0; k0 < 512; k0 += 64) {
        __syncthreads();
        if (k0 + 64 < 512) {
            const int nxt = cur ^ 1;
#pragma unroll
            for (int i = 0; i < 2; i++) g2lds16(Ab + goff[i] + k0 + 64, la[nxt][i]);
#pragma unroll
            for (int i = 0; i < 2; i++) g2lds16(Bb + goff[i] + k0 + 64, lb[nxt][i]);
        }
        const f16* Ac = &As[cur][0];
        const f16* Bc = &Bs[cur][0];
#pragma unroll
        for (int kk = 0; kk < 2; kk++) {
            half8 a[2], b[2];
#pragma unroll
            for (int t = 0; t < 2; t++) {
                int rowa = wm * 32 + t * 16 + l16;
                int rowb = wn * 32 + t * 16 + l16;
                int pa8 = ((kk * 4 + qd) ^ (rowa & 7)) * 8;
                int pb8 = ((kk * 4 + qd) ^ (rowb & 7)) * 8;
                a[t] = *(const half8*)&Ac[rowa * 64 + pa8];
                b[t] = *(const half8*)&Bc[rowb * 64 + pb8];
            }
#pragma unroll
            for (int mt = 0; mt < 2; mt++)
#pragma unroll
                for (int nt = 0; nt < 2; nt++)
                    acc[mt][nt] = MFMA16(a[mt], b[nt], acc[mt][nt]);
        }
        cur ^= 1;
    }

#pragma unroll
    for (int mt = 0; mt < 2; mt++)
#pragma unroll
        for (int nt = 0; nt < 2; nt++)
#pragma unroll
            for (int r = 0; r < 4; r++) {
                size_t row = m0 + wm * 32 + mt * 16 + qd * 4 + r;
                size_t col = n0 + wn * 32 + nt * 16 + l16;
                Fout[row * 512 + col] = acc[mt][nt][r] + bias[col];
            }
}

extern "C" void kernel_launch(void* const* d_in, const int* in_sizes, int n_in,
                              void* d_out, int out_size, void* d_ws, size_t ws_size,
                              hipStream_t stream) {
    const float* left  = (const float*)d_in[0];
    const float* right = (const float*)d_in[1];
    const void*  mask  = d_in[2];
    const float* Wq    = (const float*)d_in[3];
    const float* Wkv   = (const float*)d_in[4];
    const float* Wout  = (const float*)d_in[5];
    const float* bout  = (const float*)d_in[6];

    char* ws = (char*)d_ws;
    size_t off = 0;
    auto take = [&](size_t bytes) { char* p = ws + off; off += (bytes + 255) & ~(size_t)255; return p; };
    // ---- fixed allocations ----
    uint32* mbits = (uint32*)take((size_t)B_ * M_ * N_ / 8);           // 2 MB
    f16* woutt = (f16*)take((size_t)D_ * DQ_ * 2);                     // 0.5 MB
    f16* qb    = (f16*)take((size_t)B_ * M_ * D_ * 2);                 // 4 MB
    f16* kb    = (f16*)take((size_t)B_ * N_ * KP_ * 2);                // 18.9 MB (padded)
    f16* vt    = (f16*)take((size_t)B_ * H_ * DH_ * VP_ * 2);          // 17.3 MB (padded)
    f16* ob    = (f16*)take((size_t)B_ * M_ * D_ * 2);                 // 4 MB
    // ---- phase-overlay pool ----
    // phase 1 (prep+gemmqkv): wqt(0.5) wkvt(1)
    // phase 2 (attn+comb):    Op(32) + Lp(0.5) overlays the dead phase-1 buffers
    char* pool = (char*)take((size_t)34 * 1024 * 1024);
    f16* wqt    = (f16*)pool;
    f16* wkvt   = (f16*)(pool + (size_t)1 * 1024 * 1024);
    float* Op   = (float*)pool;                                        // 32 MB
    float* Lp   = (float*)(pool + (size_t)NSPLIT * 32 * M_ * DH_ * 4); // 0.5 MB

    // 5 dispatches total
    prep_k<<<4352, 256, 0, stream>>>(mask, mbits, Wq, wqt, Wkv, wkvt, Wout, woutt);
    gemmqkv_k<<<1152, 256, 0, stream>>>(left, wqt, right, wkvt, qb, kb, vt);
    attn_k<<<dim3(32, 8, NSPLIT), 512, 0, stream>>>(qb, kb, vt, mbits, Op, Lp);
    comb_k<<<2048, 256, 0, stream>>>(Op, Lp, ob, NSPLIT);
    gemmout_k<<<dim3(64, 8), 256, 0, stream>>>(ob, woutt, (float*)d_out, bout);
}